// Round 1
// baseline (1153.657 us; speedup 1.0000x reference)
//
#include <hip/hip_runtime.h>
#include <hip/hip_bf16.h>

#define N_NODES 100000
#define N_EDGES 1600000
#define DIM 128
#define N_GRAPHS 512
#define N_CLASSES 10
#define SCAN_CHUNK 1024
#define N_CHUNKS ((N_NODES + SCAN_CHUNK - 1) / SCAN_CHUNK)   // 98

// ---------------- CSR build ----------------

__global__ void k_zero(int* __restrict__ p, int n) {
    int i = blockIdx.x * blockDim.x + threadIdx.x;
    int stride = gridDim.x * blockDim.x;
    for (; i < n; i += stride) p[i] = 0;
}

__global__ void k_count(const int* __restrict__ dst, int* __restrict__ counts) {
    int i = blockIdx.x * blockDim.x + threadIdx.x;
    int stride = gridDim.x * blockDim.x;
    for (; i < N_EDGES; i += stride) atomicAdd(&counts[dst[i]], 1);
}

__global__ __launch_bounds__(256) void k_chunk_reduce(const int* __restrict__ counts,
                                                      int* __restrict__ chunk_sums) {
    int base = blockIdx.x * SCAN_CHUNK;
    int tid = threadIdx.x;
    int s = 0;
    for (int i = tid; i < SCAN_CHUNK; i += 256) {
        int idx = base + i;
        if (idx < N_NODES) s += counts[idx];
    }
    __shared__ int red[256];
    red[tid] = s;
    __syncthreads();
    for (int off = 128; off > 0; off >>= 1) {
        if (tid < off) red[tid] += red[tid + off];
        __syncthreads();
    }
    if (tid == 0) chunk_sums[blockIdx.x] = red[0];
}

__global__ void k_scan_chunks(int* __restrict__ chunk_sums, int* __restrict__ row_ptr) {
    if (threadIdx.x == 0 && blockIdx.x == 0) {
        int acc = 0;
        for (int i = 0; i < N_CHUNKS; i++) {
            int v = chunk_sums[i];
            chunk_sums[i] = acc;
            acc += v;
        }
        row_ptr[N_NODES] = acc;   // == N_EDGES
    }
}

__global__ __launch_bounds__(256) void k_chunk_scan(const int* __restrict__ counts,
                                                    const int* __restrict__ chunk_sums,
                                                    int* __restrict__ row_ptr) {
    int base = blockIdx.x * SCAN_CHUNK;
    int tid = threadIdx.x;               // 256 threads x 4 consecutive elems
    int i0 = base + tid * 4;
    int v[4];
    int s = 0;
    #pragma unroll
    for (int j = 0; j < 4; j++) {
        int idx = i0 + j;
        v[j] = (idx < N_NODES) ? counts[idx] : 0;
        s += v[j];
    }
    __shared__ int sc[256];
    sc[tid] = s;
    __syncthreads();
    // Hillis-Steele inclusive scan
    for (int off = 1; off < 256; off <<= 1) {
        int t = (tid >= off) ? sc[tid - off] : 0;
        __syncthreads();
        sc[tid] += t;
        __syncthreads();
    }
    int excl = sc[tid] - s + chunk_sums[blockIdx.x];
    #pragma unroll
    for (int j = 0; j < 4; j++) {
        int idx = i0 + j;
        if (idx < N_NODES) row_ptr[idx] = excl;
        excl += v[j];
    }
}

__global__ void k_copy(const int* __restrict__ src, int* __restrict__ dst, int n) {
    int i = blockIdx.x * blockDim.x + threadIdx.x;
    int stride = gridDim.x * blockDim.x;
    for (; i < n; i += stride) dst[i] = src[i];
}

__global__ void k_fill(const int* __restrict__ srcv, const int* __restrict__ dstv,
                       int* __restrict__ cursor, int* __restrict__ col) {
    int i = blockIdx.x * blockDim.x + threadIdx.x;
    int stride = gridDim.x * blockDim.x;
    for (; i < N_EDGES; i += stride) {
        int p = atomicAdd(&cursor[dstv[i]], 1);
        col[p] = srcv[i];
    }
}

// ---------------- GIN aggregation: h = x + sum_{j->i} x_j ----------------
// one wave (64 lanes) per node; lane owns 2 channels (float2); row reads are
// 64 lanes x 8B = 512B contiguous.
__global__ __launch_bounds__(256) void k_agg(const float* __restrict__ x,
                                             const int* __restrict__ row_ptr,
                                             const int* __restrict__ col,
                                             float* __restrict__ h) {
    int node = (blockIdx.x << 2) + (threadIdx.x >> 6);
    if (node >= N_NODES) return;
    int lane = threadIdx.x & 63;
    const float2* xr = (const float2*)x;
    int c = (node << 6) + lane;   // float2 index: node*64 + lane
    float2 acc = xr[c];           // (1+eps)*x with eps=0
    int b = row_ptr[node], e = row_ptr[node + 1];
    for (int j = b; j < e; j++) {
        int s = col[j];
        float2 v = xr[(s << 6) + lane];
        acc.x += v.x;
        acc.y += v.y;
    }
    ((float2*)h)[c] = acc;
}

// ---------------- fused MLP: x_out = relu( relu(h@W1+b1) @ W2 + b2 ) --------
// 64-node tile per block, 256 threads, each thread computes 4 nodes x 8 outs.
// LDS tiles padded to stride 129 -> conflict-free stride-129 column reads.
#define MLP_TILE 64
#define LDH 129

__global__ __launch_bounds__(256) void k_mlp(const float* __restrict__ hin,
                                             float* __restrict__ xout,
                                             const float* __restrict__ W1,
                                             const float* __restrict__ b1,
                                             const float* __restrict__ W2,
                                             const float* __restrict__ b2) {
    __shared__ float hT[MLP_TILE * LDH];
    __shared__ float tT[MLP_TILE * LDH];
    int tid = threadIdx.x;
    int node0 = blockIdx.x * MLP_TILE;

    // cooperative load of h tile (coalesced float4, transstore as 4x b32)
    #pragma unroll
    for (int it = 0; it < 8; ++it) {
        int idx = it * 256 + tid;        // 0..2047
        int n = idx >> 5;                // node-in-tile
        int kg = idx & 31;               // float4 group
        int gn = node0 + n;
        float4 v = (gn < N_NODES) ? ((const float4*)hin)[(size_t)gn * 32 + kg]
                                  : make_float4(0.f, 0.f, 0.f, 0.f);
        float* p = &hT[n * LDH + kg * 4];
        p[0] = v.x; p[1] = v.y; p[2] = v.z; p[3] = v.w;
    }
    __syncthreads();

    int og = tid & 15, ng = tid >> 4;
    int o0 = og * 8, n0 = ng * 4;
    float acc[4][8];

    // ---- phase A: t = relu(h @ W1 + b1) ----
    #pragma unroll
    for (int j = 0; j < 4; j++)
        #pragma unroll
        for (int o = 0; o < 8; o++) acc[j][o] = b1[o0 + o];

    #pragma unroll 4
    for (int k = 0; k < 128; k++) {
        float4 bv0 = *(const float4*)&W1[k * 128 + o0];
        float4 bv1 = *(const float4*)&W1[k * 128 + o0 + 4];
        float bb[8] = {bv0.x, bv0.y, bv0.z, bv0.w, bv1.x, bv1.y, bv1.z, bv1.w};
        float aa[4];
        #pragma unroll
        for (int j = 0; j < 4; j++) aa[j] = hT[(n0 + j) * LDH + k];
        #pragma unroll
        for (int j = 0; j < 4; j++)
            #pragma unroll
            for (int o = 0; o < 8; o++) acc[j][o] += aa[j] * bb[o];
    }
    #pragma unroll
    for (int j = 0; j < 4; j++)
        #pragma unroll
        for (int o = 0; o < 8; o++) {
            float t = acc[j][o];
            tT[(n0 + j) * LDH + o0 + o] = t > 0.f ? t : 0.f;
        }
    __syncthreads();

    // ---- phase B: x_out = relu(t @ W2 + b2) ----
    #pragma unroll
    for (int j = 0; j < 4; j++)
        #pragma unroll
        for (int o = 0; o < 8; o++) acc[j][o] = b2[o0 + o];

    #pragma unroll 4
    for (int k = 0; k < 128; k++) {
        float4 bv0 = *(const float4*)&W2[k * 128 + o0];
        float4 bv1 = *(const float4*)&W2[k * 128 + o0 + 4];
        float bb[8] = {bv0.x, bv0.y, bv0.z, bv0.w, bv1.x, bv1.y, bv1.z, bv1.w};
        float aa[4];
        #pragma unroll
        for (int j = 0; j < 4; j++) aa[j] = tT[(n0 + j) * LDH + k];
        #pragma unroll
        for (int j = 0; j < 4; j++)
            #pragma unroll
            for (int o = 0; o < 8; o++) acc[j][o] += aa[j] * bb[o];
    }
    #pragma unroll
    for (int j = 0; j < 4; j++) {
        int gn = node0 + n0 + j;
        if (gn < N_NODES) {
            #pragma unroll
            for (int o = 0; o < 8; o++) {
                float t = acc[j][o];
                xout[(size_t)gn * 128 + o0 + o] = t > 0.f ? t : 0.f;
            }
        }
    }
}

// ---------------- global add pool (batch is sorted) ----------------
__global__ __launch_bounds__(128) void k_pool(const float* __restrict__ x,
                                              const int* __restrict__ batch,
                                              float* __restrict__ pooled) {
    int g = blockIdx.x;
    int c = threadIdx.x;   // 128 channels
    // lower_bound(batch, g)
    int lo = 0, hi = N_NODES;
    while (lo < hi) { int m = (lo + hi) >> 1; if (batch[m] < g) lo = m + 1; else hi = m; }
    int start = lo;
    hi = N_NODES;
    while (lo < hi) { int m = (lo + hi) >> 1; if (batch[m] < g + 1) lo = m + 1; else hi = m; }
    int end = lo;
    float acc = 0.f;
    for (int n = start; n < end; n++) acc += x[(size_t)n * 128 + c];
    pooled[g * 128 + c] = acc;
}

__global__ __launch_bounds__(64) void k_final(const float* __restrict__ pooled,
                                              const float* __restrict__ wl,
                                              const float* __restrict__ bl,
                                              float* __restrict__ out) {
    int g = blockIdx.x;
    int o = threadIdx.x;
    if (o >= N_CLASSES) return;
    float acc = bl[o];
    for (int k = 0; k < 128; k++) acc += pooled[g * 128 + k] * wl[k * N_CLASSES + o];
    out[g * N_CLASSES + o] = acc;
}

// ---------------- launch ----------------

extern "C" void kernel_launch(void* const* d_in, const int* in_sizes, int n_in,
                              void* d_out, int out_size, void* d_ws, size_t ws_size,
                              hipStream_t stream) {
    const float* x0  = (const float*)d_in[0];
    const int* ei    = (const int*)d_in[1];      // [2, E]
    const int* batch = (const int*)d_in[2];
    const float* W1[3] = {(const float*)d_in[3], (const float*)d_in[7],  (const float*)d_in[11]};
    const float* B1[3] = {(const float*)d_in[4], (const float*)d_in[8],  (const float*)d_in[12]};
    const float* W2[3] = {(const float*)d_in[5], (const float*)d_in[9],  (const float*)d_in[13]};
    const float* B2[3] = {(const float*)d_in[6], (const float*)d_in[10], (const float*)d_in[14]};
    const float* wl = (const float*)d_in[15];
    const float* bl = (const float*)d_in[16];
    float* out = (float*)d_out;

    const int* srcv = ei;
    const int* dstv = ei + N_EDGES;

    // workspace layout
    char* w = (char*)d_ws;
    float* hbuf = (float*)w;                                   // N*128
    float* xbuf = hbuf + (size_t)N_NODES * DIM;                // N*128
    float* pooled = xbuf + (size_t)N_NODES * DIM;              // 512*128
    int* row_ptr = (int*)(pooled + N_GRAPHS * DIM);            // N+1
    int* cursor  = row_ptr + (N_NODES + 2);                    // N
    int* colidx  = cursor + N_NODES;                           // E
    int* chunk_sums = colidx + N_EDGES;                        // N_CHUNKS

    // ---- CSR build (once per call; reused by all 3 layers) ----
    hipLaunchKernelGGL(k_zero, dim3(512), dim3(256), 0, stream, cursor, N_NODES);
    hipLaunchKernelGGL(k_count, dim3(2048), dim3(256), 0, stream, dstv, cursor);
    hipLaunchKernelGGL(k_chunk_reduce, dim3(N_CHUNKS), dim3(256), 0, stream, cursor, chunk_sums);
    hipLaunchKernelGGL(k_scan_chunks, dim3(1), dim3(64), 0, stream, chunk_sums, row_ptr);
    hipLaunchKernelGGL(k_chunk_scan, dim3(N_CHUNKS), dim3(256), 0, stream, cursor, chunk_sums, row_ptr);
    hipLaunchKernelGGL(k_copy, dim3(512), dim3(256), 0, stream, row_ptr, cursor, N_NODES);
    hipLaunchKernelGGL(k_fill, dim3(2048), dim3(256), 0, stream, srcv, dstv, cursor, colidx);

    // ---- 3 GIN layers ----
    dim3 aggGrid((N_NODES + 3) / 4), aggBlk(256);
    dim3 mlpGrid((N_NODES + MLP_TILE - 1) / MLP_TILE), mlpBlk(256);
    const float* xin = x0;
    for (int l = 0; l < 3; l++) {
        hipLaunchKernelGGL(k_agg, aggGrid, aggBlk, 0, stream, xin, row_ptr, colidx, hbuf);
        hipLaunchKernelGGL(k_mlp, mlpGrid, mlpBlk, 0, stream, hbuf, xbuf,
                           W1[l], B1[l], W2[l], B2[l]);
        xin = xbuf;
    }

    // ---- pool + final linear ----
    hipLaunchKernelGGL(k_pool, dim3(N_GRAPHS), dim3(128), 0, stream, xbuf, batch, pooled);
    hipLaunchKernelGGL(k_final, dim3(N_GRAPHS), dim3(64), 0, stream, pooled, wl, bl, out);
}

// Round 2
// 819.837 us; speedup vs baseline: 1.4072x; 1.4072x over previous
//
#include <hip/hip_runtime.h>
#include <hip/hip_bf16.h>

#define N_NODES 100000
#define N_EDGES 1600000
#define DIM 128
#define N_GRAPHS 512
#define N_CLASSES 10
#define SCAN_CHUNK 1024
#define N_CHUNKS ((N_NODES + SCAN_CHUNK - 1) / SCAN_CHUNK)   // 98

typedef __attribute__((ext_vector_type(8))) short short8;
typedef __attribute__((ext_vector_type(4))) float floatx4;

__device__ __forceinline__ uint bfround(float f) {   // fp32 -> bf16 bits (RNE)
    uint u = __builtin_bit_cast(uint, f);
    return (u + 0x7fffu + ((u >> 16) & 1u)) >> 16;
}
__device__ __forceinline__ float bflo(uint u) { return __builtin_bit_cast(float, u << 16); }
__device__ __forceinline__ float bfhi(uint u) { return __builtin_bit_cast(float, u & 0xffff0000u); }
__device__ __forceinline__ float bf2f(ushort u) { return __builtin_bit_cast(float, (uint)u << 16); }

// ---------------- dtype conversion ----------------

__global__ void k_cvt_x(const float* __restrict__ x, ushort* __restrict__ xb, int n4) {
    int i = blockIdx.x * blockDim.x + threadIdx.x;
    int stride = gridDim.x * blockDim.x;
    for (; i < n4; i += stride) {
        floatx4 v = *(const floatx4*)(x + (size_t)i * 4);
        ushort4 o;
        o.x = (ushort)bfround(v.x);
        o.y = (ushort)bfround(v.y);
        o.z = (ushort)bfround(v.z);
        o.w = (ushort)bfround(v.w);
        *(ushort4*)(xb + (size_t)i * 4) = o;
    }
}

// W [K=128][N=128] fp32 -> Wt [N][K] bf16 (transposed so B-fragments are contiguous K)
__global__ __launch_bounds__(256) void k_cvt_w(const float* __restrict__ W, ushort* __restrict__ Wt) {
    int idx = blockIdx.x * 256 + threadIdx.x;   // grid 64 -> 16384
    int n = idx >> 7, k = idx & 127;
    Wt[idx] = (ushort)bfround(W[k * 128 + n]);
}

// ---------------- CSR build ----------------

__global__ void k_zero(int* __restrict__ p, int n) {
    int i = blockIdx.x * blockDim.x + threadIdx.x;
    int stride = gridDim.x * blockDim.x;
    for (; i < n; i += stride) p[i] = 0;
}

__global__ void k_count(const int* __restrict__ dst, int* __restrict__ counts) {
    int i = blockIdx.x * blockDim.x + threadIdx.x;
    int stride = gridDim.x * blockDim.x;
    for (; i < N_EDGES; i += stride) atomicAdd(&counts[dst[i]], 1);
}

__global__ __launch_bounds__(256) void k_chunk_reduce(const int* __restrict__ counts,
                                                      int* __restrict__ chunk_sums) {
    int base = blockIdx.x * SCAN_CHUNK;
    int tid = threadIdx.x;
    int s = 0;
    for (int i = tid; i < SCAN_CHUNK; i += 256) {
        int idx = base + i;
        if (idx < N_NODES) s += counts[idx];
    }
    __shared__ int red[256];
    red[tid] = s;
    __syncthreads();
    for (int off = 128; off > 0; off >>= 1) {
        if (tid < off) red[tid] += red[tid + off];
        __syncthreads();
    }
    if (tid == 0) chunk_sums[blockIdx.x] = red[0];
}

__global__ void k_scan_chunks(int* __restrict__ chunk_sums, int* __restrict__ row_ptr) {
    if (threadIdx.x == 0 && blockIdx.x == 0) {
        int acc = 0;
        for (int i = 0; i < N_CHUNKS; i++) {
            int v = chunk_sums[i];
            chunk_sums[i] = acc;
            acc += v;
        }
        row_ptr[N_NODES] = acc;
    }
}

__global__ __launch_bounds__(256) void k_chunk_scan(const int* __restrict__ counts,
                                                    const int* __restrict__ chunk_sums,
                                                    int* __restrict__ row_ptr) {
    int base = blockIdx.x * SCAN_CHUNK;
    int tid = threadIdx.x;
    int i0 = base + tid * 4;
    int v[4];
    int s = 0;
    #pragma unroll
    for (int j = 0; j < 4; j++) {
        int idx = i0 + j;
        v[j] = (idx < N_NODES) ? counts[idx] : 0;
        s += v[j];
    }
    __shared__ int sc[256];
    sc[tid] = s;
    __syncthreads();
    for (int off = 1; off < 256; off <<= 1) {
        int t = (tid >= off) ? sc[tid - off] : 0;
        __syncthreads();
        sc[tid] += t;
        __syncthreads();
    }
    int excl = sc[tid] - s + chunk_sums[blockIdx.x];
    #pragma unroll
    for (int j = 0; j < 4; j++) {
        int idx = i0 + j;
        if (idx < N_NODES) row_ptr[idx] = excl;
        excl += v[j];
    }
}

__global__ void k_copy(const int* __restrict__ src, int* __restrict__ dst, int n) {
    int i = blockIdx.x * blockDim.x + threadIdx.x;
    int stride = gridDim.x * blockDim.x;
    for (; i < n; i += stride) dst[i] = src[i];
}

__global__ void k_fill(const int* __restrict__ srcv, const int* __restrict__ dstv,
                       int* __restrict__ cursor, int* __restrict__ col) {
    int i = blockIdx.x * blockDim.x + threadIdx.x;
    int stride = gridDim.x * blockDim.x;
    for (; i < N_EDGES; i += stride) {
        int p = atomicAdd(&cursor[dstv[i]], 1);
        col[p] = srcv[i];
    }
}

// ---------------- GIN aggregation (bf16 rows, fp32 accum) ----------------
// one wave per node; lane owns 2 channels (one uint = bf16x2); 256B/row coalesced.
__global__ __launch_bounds__(256) void k_agg(const uint* __restrict__ x,
                                             const int* __restrict__ row_ptr,
                                             const int* __restrict__ col,
                                             uint* __restrict__ h) {
    int node = (blockIdx.x << 2) + (threadIdx.x >> 6);
    if (node >= N_NODES) return;
    int lane = threadIdx.x & 63;
    int c = (node << 6) + lane;
    uint u = x[c];
    float ax = bflo(u), ay = bfhi(u);
    int b = row_ptr[node], e = row_ptr[node + 1];
    for (int j = b; j < e; j++) {
        int s = col[j];
        uint v = x[(s << 6) + lane];
        ax += bflo(v);
        ay += bfhi(v);
    }
    h[c] = bfround(ax) | (bfround(ay) << 16);
}

// ---------------- fused MFMA MLP ----------------
// 64-node tile, 256 threads (4 waves), wave w owns N-cols [w*32, w*32+32).
// LDS tiles [64][256B] with XOR swizzle (byte ^= (row&7)<<4) -> conflict-free b128 reads.

__device__ __forceinline__ int loff(int row, int byte) {
    return row * 256 + (byte ^ ((row & 7) << 4));
}

__global__ __launch_bounds__(256) void k_mlp(const ushort* __restrict__ hin,
                                             ushort* __restrict__ xout,
                                             const ushort* __restrict__ W1t,
                                             const float* __restrict__ b1,
                                             const ushort* __restrict__ W2t,
                                             const float* __restrict__ b2) {
    __shared__ alignas(16) char hT[64 * 256];
    __shared__ alignas(16) char tT[64 * 256];
    int tid = threadIdx.x;
    int lane = tid & 63;
    int wave = tid >> 6;
    int node0 = blockIdx.x * 64;
    int l15 = lane & 15;
    int lhi = lane >> 4;          // 0..3

    // ---- cooperative load: 64 rows x 256B, swizzled ----
    #pragma unroll
    for (int it = 0; it < 4; ++it) {
        int idx = it * 256 + tid;
        int row = idx >> 4;
        int cb = (idx & 15) * 16;
        int gn = node0 + row;
        floatx4 v = {0.f, 0.f, 0.f, 0.f};
        if (gn < N_NODES) v = *(const floatx4*)(hin + (size_t)gn * 128 + cb / 2);
        *(floatx4*)(hT + loff(row, cb)) = v;
    }
    __syncthreads();

    int ncol0 = wave * 32;
    // ---- B1 fragments: Wt[N][K], lane reads 8 contiguous K ----
    short8 bf[4][2];
    #pragma unroll
    for (int ks = 0; ks < 4; ks++)
        #pragma unroll
        for (int nf = 0; nf < 2; nf++) {
            int nrow = ncol0 + nf * 16 + l15;
            bf[ks][nf] = *(const short8*)(W1t + nrow * 128 + ks * 32 + lhi * 8);
        }

    floatx4 acc[4][2];
    #pragma unroll
    for (int m = 0; m < 4; m++)
        #pragma unroll
        for (int nf = 0; nf < 2; nf++) {
            float bias = b1[ncol0 + nf * 16 + l15];
            acc[m][nf] = (floatx4){bias, bias, bias, bias};
        }

    // ---- phase A: t = relu(h @ W1 + b1) ----
    #pragma unroll
    for (int ks = 0; ks < 4; ks++) {
        short8 af[4];
        #pragma unroll
        for (int m = 0; m < 4; m++)
            af[m] = *(const short8*)(hT + loff(m * 16 + l15, ks * 64 + lhi * 16));
        #pragma unroll
        for (int m = 0; m < 4; m++)
            #pragma unroll
            for (int nf = 0; nf < 2; nf++)
                acc[m][nf] = __builtin_amdgcn_mfma_f32_16x16x32_bf16(af[m], bf[ks][nf], acc[m][nf], 0, 0, 0);
    }
    #pragma unroll
    for (int m = 0; m < 4; m++)
        #pragma unroll
        for (int nf = 0; nf < 2; nf++) {
            int colb = (ncol0 + nf * 16 + l15) * 2;
            #pragma unroll
            for (int j = 0; j < 4; j++) {
                int row = m * 16 + lhi * 4 + j;
                float t = acc[m][nf][j];
                t = t > 0.f ? t : 0.f;
                *(ushort*)(tT + loff(row, colb)) = (ushort)bfround(t);
            }
        }
    __syncthreads();

    // ---- B2 fragments ----
    #pragma unroll
    for (int ks = 0; ks < 4; ks++)
        #pragma unroll
        for (int nf = 0; nf < 2; nf++) {
            int nrow = ncol0 + nf * 16 + l15;
            bf[ks][nf] = *(const short8*)(W2t + nrow * 128 + ks * 32 + lhi * 8);
        }
    #pragma unroll
    for (int m = 0; m < 4; m++)
        #pragma unroll
        for (int nf = 0; nf < 2; nf++) {
            float bias = b2[ncol0 + nf * 16 + l15];
            acc[m][nf] = (floatx4){bias, bias, bias, bias};
        }

    // ---- phase B: x = relu(t @ W2 + b2) ----
    #pragma unroll
    for (int ks = 0; ks < 4; ks++) {
        short8 af[4];
        #pragma unroll
        for (int m = 0; m < 4; m++)
            af[m] = *(const short8*)(tT + loff(m * 16 + l15, ks * 64 + lhi * 16));
        #pragma unroll
        for (int m = 0; m < 4; m++)
            #pragma unroll
            for (int nf = 0; nf < 2; nf++)
                acc[m][nf] = __builtin_amdgcn_mfma_f32_16x16x32_bf16(af[m], bf[ks][nf], acc[m][nf], 0, 0, 0);
    }
    // stage result in hT (swizzled), then coalesced store
    #pragma unroll
    for (int m = 0; m < 4; m++)
        #pragma unroll
        for (int nf = 0; nf < 2; nf++) {
            int colb = (ncol0 + nf * 16 + l15) * 2;
            #pragma unroll
            for (int j = 0; j < 4; j++) {
                int row = m * 16 + lhi * 4 + j;
                float t = acc[m][nf][j];
                t = t > 0.f ? t : 0.f;
                *(ushort*)(hT + loff(row, colb)) = (ushort)bfround(t);
            }
        }
    __syncthreads();
    #pragma unroll
    for (int it = 0; it < 4; ++it) {
        int idx = it * 256 + tid;
        int row = idx >> 4;
        int cb = (idx & 15) * 16;
        int gn = node0 + row;
        if (gn < N_NODES)
            *(floatx4*)(xout + (size_t)gn * 128 + cb / 2) = *(const floatx4*)(hT + loff(row, cb));
    }
}

// ---------------- global add pool (batch sorted) ----------------
__global__ __launch_bounds__(128) void k_pool(const ushort* __restrict__ x,
                                              const int* __restrict__ batch,
                                              float* __restrict__ pooled) {
    int g = blockIdx.x;
    int c = threadIdx.x;
    int lo = 0, hi = N_NODES;
    while (lo < hi) { int m = (lo + hi) >> 1; if (batch[m] < g) lo = m + 1; else hi = m; }
    int start = lo;
    hi = N_NODES;
    while (lo < hi) { int m = (lo + hi) >> 1; if (batch[m] < g + 1) lo = m + 1; else hi = m; }
    int end = lo;
    float acc = 0.f;
    for (int n = start; n < end; n++) acc += bf2f(x[(size_t)n * 128 + c]);
    pooled[g * 128 + c] = acc;
}

__global__ __launch_bounds__(64) void k_final(const float* __restrict__ pooled,
                                              const float* __restrict__ wl,
                                              const float* __restrict__ bl,
                                              float* __restrict__ out) {
    int g = blockIdx.x;
    int o = threadIdx.x;
    if (o >= N_CLASSES) return;
    float acc = bl[o];
    for (int k = 0; k < 128; k++) acc += pooled[g * 128 + k] * wl[k * N_CLASSES + o];
    out[g * N_CLASSES + o] = acc;
}

// ---------------- launch ----------------

extern "C" void kernel_launch(void* const* d_in, const int* in_sizes, int n_in,
                              void* d_out, int out_size, void* d_ws, size_t ws_size,
                              hipStream_t stream) {
    const float* x0  = (const float*)d_in[0];
    const int* ei    = (const int*)d_in[1];
    const int* batch = (const int*)d_in[2];
    const float* W1[3] = {(const float*)d_in[3], (const float*)d_in[7],  (const float*)d_in[11]};
    const float* B1[3] = {(const float*)d_in[4], (const float*)d_in[8],  (const float*)d_in[12]};
    const float* W2[3] = {(const float*)d_in[5], (const float*)d_in[9],  (const float*)d_in[13]};
    const float* B2[3] = {(const float*)d_in[6], (const float*)d_in[10], (const float*)d_in[14]};
    const float* wl = (const float*)d_in[15];
    const float* bl = (const float*)d_in[16];
    float* out = (float*)d_out;

    const int* srcv = ei;
    const int* dstv = ei + N_EDGES;

    // workspace layout (16B-aligned blocks)
    char* w = (char*)d_ws;
    ushort* xb = (ushort*)w;                                   // N*128 bf16
    ushort* hb = xb + (size_t)N_NODES * DIM;                   // N*128 bf16
    ushort* wt = hb + (size_t)N_NODES * DIM;                   // 6 * 128*128 bf16
    float* pooled = (float*)(wt + 6 * 128 * 128);              // 512*128 f32
    int* row_ptr = (int*)(pooled + N_GRAPHS * DIM);            // N+1
    int* cursor  = row_ptr + (N_NODES + 2);                    // N
    int* colidx  = cursor + N_NODES;                           // E
    int* chunk_sums = colidx + N_EDGES;                        // N_CHUNKS

    // ---- dtype conversion ----
    hipLaunchKernelGGL(k_cvt_x, dim3(2048), dim3(256), 0, stream, x0, xb, N_NODES * DIM / 4);
    const float* wsrc[6] = {W1[0], W2[0], W1[1], W2[1], W1[2], W2[2]};
    for (int i = 0; i < 6; i++)
        hipLaunchKernelGGL(k_cvt_w, dim3(64), dim3(256), 0, stream, wsrc[i], wt + (size_t)i * 16384);

    // ---- CSR build ----
    hipLaunchKernelGGL(k_zero, dim3(512), dim3(256), 0, stream, cursor, N_NODES);
    hipLaunchKernelGGL(k_count, dim3(2048), dim3(256), 0, stream, dstv, cursor);
    hipLaunchKernelGGL(k_chunk_reduce, dim3(N_CHUNKS), dim3(256), 0, stream, cursor, chunk_sums);
    hipLaunchKernelGGL(k_scan_chunks, dim3(1), dim3(64), 0, stream, chunk_sums, row_ptr);
    hipLaunchKernelGGL(k_chunk_scan, dim3(N_CHUNKS), dim3(256), 0, stream, cursor, chunk_sums, row_ptr);
    hipLaunchKernelGGL(k_copy, dim3(512), dim3(256), 0, stream, row_ptr, cursor, N_NODES);
    hipLaunchKernelGGL(k_fill, dim3(2048), dim3(256), 0, stream, srcv, dstv, cursor, colidx);

    // ---- 3 GIN layers: agg (xb -> hb), mlp (hb -> xb) ----
    dim3 aggGrid((N_NODES + 3) / 4), aggBlk(256);
    dim3 mlpGrid((N_NODES + 63) / 64), mlpBlk(256);
    for (int l = 0; l < 3; l++) {
        hipLaunchKernelGGL(k_agg, aggGrid, aggBlk, 0, stream,
                           (const uint*)xb, row_ptr, colidx, (uint*)hb);
        hipLaunchKernelGGL(k_mlp, mlpGrid, mlpBlk, 0, stream,
                           hb, xb, wt + (size_t)(2 * l) * 16384, B1[l],
                           wt + (size_t)(2 * l + 1) * 16384, B2[l]);
    }

    // ---- pool + final ----
    hipLaunchKernelGGL(k_pool, dim3(N_GRAPHS), dim3(128), 0, stream, xb, batch, pooled);
    hipLaunchKernelGGL(k_final, dim3(N_GRAPHS), dim3(64), 0, stream, pooled, wl, bl, out);
}

// Round 4
// 544.583 us; speedup vs baseline: 2.1184x; 1.5054x over previous
//
#include <hip/hip_runtime.h>
#include <hip/hip_bf16.h>

#define N_NODES 100000
#define N_EDGES 1600000
#define DIM 128
#define N_GRAPHS 512
#define N_CLASSES 10
#define SCAN_CHUNK 1024
#define N_CHUNKS ((N_NODES + SCAN_CHUNK - 1) / SCAN_CHUNK)   // 98

typedef __attribute__((ext_vector_type(8))) short short8;
typedef __attribute__((ext_vector_type(4))) float floatx4;

__device__ __forceinline__ uint bfround(float f) {   // fp32 -> bf16 bits (RNE)
    uint u = __builtin_bit_cast(uint, f);
    return (u + 0x7fffu + ((u >> 16) & 1u)) >> 16;
}
__device__ __forceinline__ float bflo(uint u) { return __builtin_bit_cast(float, u << 16); }
__device__ __forceinline__ float bfhi(uint u) { return __builtin_bit_cast(float, u & 0xffff0000u); }
__device__ __forceinline__ float bf2f(ushort u) { return __builtin_bit_cast(float, (uint)u << 16); }

__device__ __forceinline__ void addrow(float* a, uint4 v) {
    a[0] += bflo(v.x); a[1] += bfhi(v.x);
    a[2] += bflo(v.y); a[3] += bfhi(v.y);
    a[4] += bflo(v.z); a[5] += bfhi(v.z);
    a[6] += bflo(v.w); a[7] += bfhi(v.w);
}

// ---------------- dtype conversion ----------------

__global__ void k_cvt_x(const float* __restrict__ x, ushort* __restrict__ xb, int n4) {
    int i = blockIdx.x * blockDim.x + threadIdx.x;
    int stride = gridDim.x * blockDim.x;
    for (; i < n4; i += stride) {
        floatx4 v = *(const floatx4*)(x + (size_t)i * 4);
        ushort4 o;
        o.x = (ushort)bfround(v.x);
        o.y = (ushort)bfround(v.y);
        o.z = (ushort)bfround(v.z);
        o.w = (ushort)bfround(v.w);
        *(ushort4*)(xb + (size_t)i * 4) = o;
    }
}

struct WPtrs { const float* w[6]; };

// W [K=128][N=128] fp32 -> Wt [N][K] bf16, 6 matrices in one launch (grid 6*64)
__global__ __launch_bounds__(256) void k_cvt_w(WPtrs wp, ushort* __restrict__ Wt) {
    int m = blockIdx.x >> 6;
    int idx = (blockIdx.x & 63) * 256 + threadIdx.x;   // 0..16383
    int n = idx >> 7, k = idx & 127;
    Wt[(size_t)m * 16384 + idx] = (ushort)bfround(wp.w[m][k * 128 + n]);
}

// ---------------- CSR build ----------------

__global__ void k_zero(int* __restrict__ p, int n) {
    int i = blockIdx.x * blockDim.x + threadIdx.x;
    int stride = gridDim.x * blockDim.x;
    for (; i < n; i += stride) p[i] = 0;
}

__global__ void k_count(const int* __restrict__ dst, int* __restrict__ counts) {
    int i = blockIdx.x * blockDim.x + threadIdx.x;
    int stride = gridDim.x * blockDim.x;
    for (; i < N_EDGES; i += stride) atomicAdd(&counts[dst[i]], 1);
}

__global__ __launch_bounds__(256) void k_chunk_reduce(const int* __restrict__ counts,
                                                      int* __restrict__ chunk_sums) {
    int base = blockIdx.x * SCAN_CHUNK;
    int tid = threadIdx.x;
    int s = 0;
    for (int i = tid; i < SCAN_CHUNK; i += 256) {
        int idx = base + i;
        if (idx < N_NODES) s += counts[idx];
    }
    __shared__ int red[256];
    red[tid] = s;
    __syncthreads();
    for (int off = 128; off > 0; off >>= 1) {
        if (tid < off) red[tid] += red[tid + off];
        __syncthreads();
    }
    if (tid == 0) chunk_sums[blockIdx.x] = red[0];
}

// parallel exclusive scan of N_CHUNKS (<=128) chunk sums
__global__ __launch_bounds__(128) void k_scan_chunks(int* __restrict__ chunk_sums,
                                                     int* __restrict__ row_ptr) {
    __shared__ int s[128];
    int tid = threadIdx.x;
    int v = (tid < N_CHUNKS) ? chunk_sums[tid] : 0;
    s[tid] = v;
    __syncthreads();
    for (int off = 1; off < 128; off <<= 1) {
        int t = (tid >= off) ? s[tid - off] : 0;
        __syncthreads();
        s[tid] += t;
        __syncthreads();
    }
    if (tid < N_CHUNKS) chunk_sums[tid] = s[tid] - v;   // exclusive
    if (tid == N_CHUNKS - 1) row_ptr[N_NODES] = s[tid];
}

// scan within chunk; writes BOTH row_ptr and cursor (k_copy folded in)
__global__ __launch_bounds__(256) void k_chunk_scan(int* __restrict__ counts_and_cursor,
                                                    const int* __restrict__ chunk_sums,
                                                    int* __restrict__ row_ptr) {
    int base = blockIdx.x * SCAN_CHUNK;
    int tid = threadIdx.x;
    int i0 = base + tid * 4;
    int v[4];
    int s = 0;
    #pragma unroll
    for (int j = 0; j < 4; j++) {
        int idx = i0 + j;
        v[j] = (idx < N_NODES) ? counts_and_cursor[idx] : 0;
        s += v[j];
    }
    __shared__ int sc[256];
    sc[tid] = s;
    __syncthreads();
    for (int off = 1; off < 256; off <<= 1) {
        int t = (tid >= off) ? sc[tid - off] : 0;
        __syncthreads();
        sc[tid] += t;
        __syncthreads();
    }
    int excl = sc[tid] - s + chunk_sums[blockIdx.x];
    #pragma unroll
    for (int j = 0; j < 4; j++) {
        int idx = i0 + j;
        if (idx < N_NODES) {
            row_ptr[idx] = excl;
            counts_and_cursor[idx] = excl;   // cursor for k_fill
        }
        excl += v[j];
    }
}

__global__ void k_fill(const int* __restrict__ srcv, const int* __restrict__ dstv,
                       int* __restrict__ cursor, int* __restrict__ col) {
    int i = blockIdx.x * blockDim.x + threadIdx.x;
    int stride = gridDim.x * blockDim.x;
    for (; i < N_EDGES; i += stride) {
        int p = atomicAdd(&cursor[dstv[i]], 1);
        col[p] = srcv[i];
    }
}

// ---------------- GIN aggregation (bf16 rows, fp32 accum, 4-edge ILP) ------
// one wave per node. Edge p handled by group p&3 at block f=p>>4, slot (p>>2)&3.
// UNIFORM trip counts everywhere: every __shfl is executed by all 64 lanes and
// source-lane indices are clamped to 0 (lane 0 always holds a valid col index),
// because ds_bpermute from an exec-masked-off lane is undefined (R3 bug).
// Loads are unconditional (clamped index is a valid node row); adds predicated.
__global__ __launch_bounds__(256) void k_agg(const uint4* __restrict__ xr,
                                             const int* __restrict__ row_ptr,
                                             const int* __restrict__ col,
                                             uint4* __restrict__ hr) {
    int node = (blockIdx.x << 2) + (threadIdx.x >> 6);
    if (node >= N_NODES) return;
    int lane = threadIdx.x & 63;
    int grp = lane >> 4;
    int l16 = lane & 15;

    float acc[8];
    if (grp == 0) {
        uint4 sv = xr[(size_t)node * 16 + l16];    // self term (eps=0)
        acc[0] = bflo(sv.x); acc[1] = bfhi(sv.x);
        acc[2] = bflo(sv.y); acc[3] = bfhi(sv.y);
        acc[4] = bflo(sv.z); acc[5] = bfhi(sv.z);
        acc[6] = bflo(sv.w); acc[7] = bfhi(sv.w);
    } else {
        #pragma unroll
        for (int i = 0; i < 8; i++) acc[i] = 0.f;
    }

    int b = row_ptr[node], e = row_ptr[node + 1];
    for (int j0 = b; j0 < e; j0 += 64) {
        int rem = e - j0;
        int chunk = rem < 64 ? rem : 64;
        int myidx = (lane < chunk) ? col[j0 + lane] : 0;
        int iters = (chunk + 15) >> 4;          // wave-uniform
        for (int f = 0; f < iters; f++) {
            int p = (f << 4) + grp;
            int s0 = __shfl(myidx, (p      < chunk) ? p      : 0);
            int s1 = __shfl(myidx, (p + 4  < chunk) ? p + 4  : 0);
            int s2 = __shfl(myidx, (p + 8  < chunk) ? p + 8  : 0);
            int s3 = __shfl(myidx, (p + 12 < chunk) ? p + 12 : 0);
            uint4 v0 = xr[(size_t)s0 * 16 + l16];   // 4 loads in flight
            uint4 v1 = xr[(size_t)s1 * 16 + l16];
            uint4 v2 = xr[(size_t)s2 * 16 + l16];
            uint4 v3 = xr[(size_t)s3 * 16 + l16];
            if (p < chunk)      addrow(acc, v0);
            if (p + 4 < chunk)  addrow(acc, v1);
            if (p + 8 < chunk)  addrow(acc, v2);
            if (p + 12 < chunk) addrow(acc, v3);
        }
    }

    // cross-group reduce: groups 0..3 hold partials for the same channel set
    #pragma unroll
    for (int i = 0; i < 8; i++) {
        acc[i] += __shfl_xor(acc[i], 16);
        acc[i] += __shfl_xor(acc[i], 32);
    }

    if (grp == 0) {
        uint4 o;
        o.x = bfround(acc[0]) | (bfround(acc[1]) << 16);
        o.y = bfround(acc[2]) | (bfround(acc[3]) << 16);
        o.z = bfround(acc[4]) | (bfround(acc[5]) << 16);
        o.w = bfround(acc[6]) | (bfround(acc[7]) << 16);
        hr[(size_t)node * 16 + l16] = o;
    }
}

// ---------------- fused MFMA MLP ----------------
__device__ __forceinline__ int loff(int row, int byte) {
    return row * 256 + (byte ^ ((row & 7) << 4));
}

__global__ __launch_bounds__(256) void k_mlp(const ushort* __restrict__ hin,
                                             ushort* __restrict__ xout,
                                             const ushort* __restrict__ W1t,
                                             const float* __restrict__ b1,
                                             const ushort* __restrict__ W2t,
                                             const float* __restrict__ b2) {
    __shared__ alignas(16) char hT[64 * 256];
    __shared__ alignas(16) char tT[64 * 256];
    int tid = threadIdx.x;
    int lane = tid & 63;
    int wave = tid >> 6;
    int node0 = blockIdx.x * 64;
    int l15 = lane & 15;
    int lhi = lane >> 4;

    #pragma unroll
    for (int it = 0; it < 4; ++it) {
        int idx = it * 256 + tid;
        int row = idx >> 4;
        int cb = (idx & 15) * 16;
        int gn = node0 + row;
        floatx4 v = {0.f, 0.f, 0.f, 0.f};
        if (gn < N_NODES) v = *(const floatx4*)(hin + (size_t)gn * 128 + cb / 2);
        *(floatx4*)(hT + loff(row, cb)) = v;
    }
    __syncthreads();

    int ncol0 = wave * 32;
    short8 bf[4][2];
    #pragma unroll
    for (int ks = 0; ks < 4; ks++)
        #pragma unroll
        for (int nf = 0; nf < 2; nf++) {
            int nrow = ncol0 + nf * 16 + l15;
            bf[ks][nf] = *(const short8*)(W1t + nrow * 128 + ks * 32 + lhi * 8);
        }

    floatx4 acc[4][2];
    #pragma unroll
    for (int m = 0; m < 4; m++)
        #pragma unroll
        for (int nf = 0; nf < 2; nf++) {
            float bias = b1[ncol0 + nf * 16 + l15];
            acc[m][nf] = (floatx4){bias, bias, bias, bias};
        }

    #pragma unroll
    for (int ks = 0; ks < 4; ks++) {
        short8 af[4];
        #pragma unroll
        for (int m = 0; m < 4; m++)
            af[m] = *(const short8*)(hT + loff(m * 16 + l15, ks * 64 + lhi * 16));
        #pragma unroll
        for (int m = 0; m < 4; m++)
            #pragma unroll
            for (int nf = 0; nf < 2; nf++)
                acc[m][nf] = __builtin_amdgcn_mfma_f32_16x16x32_bf16(af[m], bf[ks][nf], acc[m][nf], 0, 0, 0);
    }
    #pragma unroll
    for (int m = 0; m < 4; m++)
        #pragma unroll
        for (int nf = 0; nf < 2; nf++) {
            int colb = (ncol0 + nf * 16 + l15) * 2;
            #pragma unroll
            for (int j = 0; j < 4; j++) {
                int row = m * 16 + lhi * 4 + j;
                float t = acc[m][nf][j];
                t = t > 0.f ? t : 0.f;
                *(ushort*)(tT + loff(row, colb)) = (ushort)bfround(t);
            }
        }
    __syncthreads();

    #pragma unroll
    for (int ks = 0; ks < 4; ks++)
        #pragma unroll
        for (int nf = 0; nf < 2; nf++) {
            int nrow = ncol0 + nf * 16 + l15;
            bf[ks][nf] = *(const short8*)(W2t + nrow * 128 + ks * 32 + lhi * 8);
        }
    #pragma unroll
    for (int m = 0; m < 4; m++)
        #pragma unroll
        for (int nf = 0; nf < 2; nf++) {
            float bias = b2[ncol0 + nf * 16 + l15];
            acc[m][nf] = (floatx4){bias, bias, bias, bias};
        }

    #pragma unroll
    for (int ks = 0; ks < 4; ks++) {
        short8 af[4];
        #pragma unroll
        for (int m = 0; m < 4; m++)
            af[m] = *(const short8*)(tT + loff(m * 16 + l15, ks * 64 + lhi * 16));
        #pragma unroll
        for (int m = 0; m < 4; m++)
            #pragma unroll
            for (int nf = 0; nf < 2; nf++)
                acc[m][nf] = __builtin_amdgcn_mfma_f32_16x16x32_bf16(af[m], bf[ks][nf], acc[m][nf], 0, 0, 0);
    }
    #pragma unroll
    for (int m = 0; m < 4; m++)
        #pragma unroll
        for (int nf = 0; nf < 2; nf++) {
            int colb = (ncol0 + nf * 16 + l15) * 2;
            #pragma unroll
            for (int j = 0; j < 4; j++) {
                int row = m * 16 + lhi * 4 + j;
                float t = acc[m][nf][j];
                t = t > 0.f ? t : 0.f;
                *(ushort*)(hT + loff(row, colb)) = (ushort)bfround(t);
            }
        }
    __syncthreads();
    #pragma unroll
    for (int it = 0; it < 4; ++it) {
        int idx = it * 256 + tid;
        int row = idx >> 4;
        int cb = (idx & 15) * 16;
        int gn = node0 + row;
        if (gn < N_NODES)
            *(floatx4*)(xout + (size_t)gn * 128 + cb / 2) = *(const floatx4*)(hT + loff(row, cb));
    }
}

// ---------------- global add pool (batch sorted) ----------------
__global__ __launch_bounds__(128) void k_pool(const ushort* __restrict__ x,
                                              const int* __restrict__ batch,
                                              float* __restrict__ pooled) {
    int g = blockIdx.x;
    int c = threadIdx.x;
    int lo = 0, hi = N_NODES;
    while (lo < hi) { int m = (lo + hi) >> 1; if (batch[m] < g) lo = m + 1; else hi = m; }
    int start = lo;
    hi = N_NODES;
    while (lo < hi) { int m = (lo + hi) >> 1; if (batch[m] < g + 1) lo = m + 1; else hi = m; }
    int end = lo;
    float acc = 0.f;
    for (int n = start; n < end; n++) acc += bf2f(x[(size_t)n * 128 + c]);
    pooled[g * 128 + c] = acc;
}

__global__ __launch_bounds__(64) void k_final(const float* __restrict__ pooled,
                                              const float* __restrict__ wl,
                                              const float* __restrict__ bl,
                                              float* __restrict__ out) {
    int g = blockIdx.x;
    int o = threadIdx.x;
    if (o >= N_CLASSES) return;
    float acc = bl[o];
    for (int k = 0; k < 128; k++) acc += pooled[g * 128 + k] * wl[k * N_CLASSES + o];
    out[g * N_CLASSES + o] = acc;
}

// ---------------- launch ----------------

extern "C" void kernel_launch(void* const* d_in, const int* in_sizes, int n_in,
                              void* d_out, int out_size, void* d_ws, size_t ws_size,
                              hipStream_t stream) {
    const float* x0  = (const float*)d_in[0];
    const int* ei    = (const int*)d_in[1];
    const int* batch = (const int*)d_in[2];
    const float* W1[3] = {(const float*)d_in[3], (const float*)d_in[7],  (const float*)d_in[11]};
    const float* B1[3] = {(const float*)d_in[4], (const float*)d_in[8],  (const float*)d_in[12]};
    const float* W2[3] = {(const float*)d_in[5], (const float*)d_in[9],  (const float*)d_in[13]};
    const float* B2[3] = {(const float*)d_in[6], (const float*)d_in[10], (const float*)d_in[14]};
    const float* wl = (const float*)d_in[15];
    const float* bl = (const float*)d_in[16];
    float* out = (float*)d_out;

    const int* srcv = ei;
    const int* dstv = ei + N_EDGES;

    // workspace layout
    char* w = (char*)d_ws;
    ushort* xb = (ushort*)w;                                   // N*128 bf16
    ushort* hb = xb + (size_t)N_NODES * DIM;                   // N*128 bf16
    ushort* wt = hb + (size_t)N_NODES * DIM;                   // 6*128*128 bf16
    float* pooled = (float*)(wt + 6 * 128 * 128);              // 512*128 f32
    int* row_ptr = (int*)(pooled + N_GRAPHS * DIM);            // N+1
    int* cursor  = row_ptr + (N_NODES + 2);                    // N (counts then cursor)
    int* colidx  = cursor + N_NODES;                           // E
    int* chunk_sums = colidx + N_EDGES;                        // N_CHUNKS

    // ---- dtype conversion ----
    hipLaunchKernelGGL(k_cvt_x, dim3(2048), dim3(256), 0, stream, x0, xb, N_NODES * DIM / 4);
    WPtrs wp;
    wp.w[0] = W1[0]; wp.w[1] = W2[0]; wp.w[2] = W1[1];
    wp.w[3] = W2[1]; wp.w[4] = W1[2]; wp.w[5] = W2[2];
    hipLaunchKernelGGL(k_cvt_w, dim3(6 * 64), dim3(256), 0, stream, wp, wt);

    // ---- CSR build ----
    hipLaunchKernelGGL(k_zero, dim3(512), dim3(256), 0, stream, cursor, N_NODES);
    hipLaunchKernelGGL(k_count, dim3(2048), dim3(256), 0, stream, dstv, cursor);
    hipLaunchKernelGGL(k_chunk_reduce, dim3(N_CHUNKS), dim3(256), 0, stream, cursor, chunk_sums);
    hipLaunchKernelGGL(k_scan_chunks, dim3(1), dim3(128), 0, stream, chunk_sums, row_ptr);
    hipLaunchKernelGGL(k_chunk_scan, dim3(N_CHUNKS), dim3(256), 0, stream, cursor, chunk_sums, row_ptr);
    hipLaunchKernelGGL(k_fill, dim3(2048), dim3(256), 0, stream, srcv, dstv, cursor, colidx);

    // ---- 3 GIN layers: agg (xb -> hb), mlp (hb -> xb) ----
    dim3 aggGrid((N_NODES + 3) / 4), aggBlk(256);
    dim3 mlpGrid((N_NODES + 63) / 64), mlpBlk(256);
    for (int l = 0; l < 3; l++) {
        hipLaunchKernelGGL(k_agg, aggGrid, aggBlk, 0, stream,
                           (const uint4*)xb, row_ptr, colidx, (uint4*)hb);
        hipLaunchKernelGGL(k_mlp, mlpGrid, mlpBlk, 0, stream,
                           hb, xb, wt + (size_t)(2 * l) * 16384, B1[l],
                           wt + (size_t)(2 * l + 1) * 16384, B2[l]);
    }

    // ---- pool + final ----
    hipLaunchKernelGGL(k_pool, dim3(N_GRAPHS), dim3(128), 0, stream, xb, batch, pooled);
    hipLaunchKernelGGL(k_final, dim3(N_GRAPHS), dim3(64), 0, stream, pooled, wl, bl, out);
}